// Round 13
// baseline (7560.507 us; speedup 1.0000x reference)
//
#include <hip/hip_runtime.h>
#include <hip/hip_bf16.h>

// Problem dims
#define SS 256
#define BB 512
#define II 46
#define HH 256
#define CC 40
#define SB (SS*BB)        // 131072 rows
#define G3 (3*HH)         // 768
#define EPSF 1e-5f
#define NPART (SB/64)     // PS/PQ capacity

typedef __attribute__((ext_vector_type(8))) short bf16x8;
typedef __attribute__((ext_vector_type(4))) float f32x4;

// ---------------------------------------------------------------------------
// helpers
// ---------------------------------------------------------------------------
__device__ __forceinline__ unsigned short f2bf_rne(float f){
  unsigned u = __float_as_uint(f);
  unsigned r = (u + 0x7FFFu + ((u >> 16) & 1u)) >> 16;
  return (unsigned short)r;
}
__device__ __forceinline__ float bf2f(unsigned short b){
  return __uint_as_float(((unsigned)b) << 16);
}
__device__ __forceinline__ void cvt8(const float* v, bf16x8& hi, bf16x8& lo){
  #pragma unroll
  for (int e=0;e<8;e++){
    unsigned short hb = f2bf_rne(v[e]);
    hi[e] = (short)hb;
    lo[e] = (short)f2bf_rne(v[e] - bf2f(hb));
  }
}

// ---------------------------------------------------------------------------
// split f32 weight array -> bf16 {hi, lo}
// ---------------------------------------------------------------------------
__global__ void split_w_k(const float* __restrict__ w, unsigned short* __restrict__ wh,
                          unsigned short* __restrict__ wl, int n){
  int i = blockIdx.x*256 + threadIdx.x;
  if (i >= n) return;
  float v = w[i];
  unsigned short hb = f2bf_rne(v);
  wh[i] = hb;
  wl[i] = f2bf_rne(v - bf2f(hb));
}

// ---------------------------------------------------------------------------
// h0[b,j] = sum_{c<6} X[0,b,40+c] * i2h_w[j,c] + i2h_b[j]  -> both carries
// ---------------------------------------------------------------------------
__global__ void h0_k(const float* __restrict__ X, const float* __restrict__ w,
                     const float* __restrict__ bias, float* __restrict__ h1c,
                     float* __restrict__ h2c){
  int b = blockIdx.x, jj = threadIdx.x;
  const float* p = X + (long long)b*II + (II - 6);
  float acc = bias[jj];
  #pragma unroll
  for (int c2=0;c2<6;c2++) acc = fmaf(p[c2], w[jj*6 + c2], acc);
  h1c[(long long)b*HH + jj] = acc;
  h2c[(long long)b*HH + jj] = acc;
}

// ---------------------------------------------------------------------------
// Pre-format whh (768x256) into MFMA B-fragment order, bf16 (R10, proven).
// ---------------------------------------------------------------------------
__global__ void wfrag_k(const float* __restrict__ whh, unsigned short* __restrict__ wf){
  int tid = blockIdx.x*256 + threadIdx.x;       // 384*64 = 24576 total
  if (tid >= 384*64) return;
  int f = tid >> 6, l = tid & 63;
  int ntile = f >> 3, kt = f & 7;
  int col = ntile*16 + (l & 15);
  int k0  = kt*32 + (l >> 4)*8;
  unsigned short* dst = wf + (((size_t)f)*64 + l)*8;
  #pragma unroll
  for (int e=0;e<8;e++) dst[e] = f2bf_rne(whh[(size_t)col*HH + k0 + e]);
}

// ---------------------------------------------------------------------------
// Generic f32 GEMM (small-K ops: comb K=80, conv1 K=40).
// MODE 0: store; 1: store relu; 2: accumulate; 3: BN-STATS ONLY.
// XM 1: A is implicit [X | Mi] with row stride II.
// ---------------------------------------------------------------------------
template<int MODE, int XM>
__global__ void gemm_tn(const float* __restrict__ A, int lda,
                        const float* __restrict__ W, int ldw,
                        const float* __restrict__ bias,
                        float* __restrict__ Co, int ldc,
                        int Mrows, int N, int K,
                        const float* __restrict__ A2, long long r0,
                        float* __restrict__ ps, float* __restrict__ pq, int pblk0)
{
  __shared__ __align__(16) float As[32][132];
  __shared__ __align__(16) float Ws[32][132];
  const int m0 = blockIdx.x*128, n0 = blockIdx.y*128;
  const int t  = threadIdx.x;
  const int tm = t >> 4, tn = t & 15;
  float acc[8][8];
  #pragma unroll
  for (int i=0;i<8;i++)
    #pragma unroll
    for (int j2=0;j2<8;j2++) acc[i][j2] = 0.f;

  for (int k0=0;k0<K;k0+=32){
    #pragma unroll
    for (int u=0;u<16;u++){
      int idx = u*256 + t;
      int r = idx >> 5, c = idx & 31;
      int gk = k0 + c;
      float av = 0.f, wv = 0.f;
      if (gk < K){
        int gm = m0 + r;
        if (gm < Mrows){
          if (XM){
            long long gr = r0 + gm;
            av = (gk < CC) ? A[gr*II + gk] : A2[gr*II + (gk - CC)];
          } else {
            av = A[(long long)gm*lda + gk];
          }
        }
        int gn = n0 + r;
        if (gn < N)     wv = W[(long long)gn*ldw + gk];
      }
      As[c][r] = av;
      Ws[c][r] = wv;
    }
    __syncthreads();
    #pragma unroll
    for (int kk=0;kk<32;kk++){
      const float4 a0 = *(const float4*)&As[kk][tm*8];
      const float4 a1 = *(const float4*)&As[kk][tm*8+4];
      const float4 b0 = *(const float4*)&Ws[kk][tn*8];
      const float4 b1 = *(const float4*)&Ws[kk][tn*8+4];
      const float av[8] = {a0.x,a0.y,a0.z,a0.w,a1.x,a1.y,a1.z,a1.w};
      const float bv[8] = {b0.x,b0.y,b0.z,b0.w,b1.x,b1.y,b1.z,b1.w};
      #pragma unroll
      for (int i=0;i<8;i++)
        #pragma unroll
        for (int j2=0;j2<8;j2++) acc[i][j2] = fmaf(av[i], bv[j2], acc[i][j2]);
    }
    __syncthreads();
  }

  if (MODE == 3){
    __shared__ float redS[16][128];
    __shared__ float redQ[16][128];
    #pragma unroll
    for (int j2=0;j2<8;j2++){
      const int gn = n0 + tn*8 + j2;
      const float bv = bias[gn];
      float s = 0.f, q = 0.f;
      #pragma unroll
      for (int i=0;i<8;i++){
        const float val = acc[i][j2] + bv;
        s += val; q = fmaf(val, val, q);
      }
      redS[tm][tn*8+j2] = s;
      redQ[tm][tn*8+j2] = q;
    }
    __syncthreads();
    if (t < 128){
      float ss = 0.f, qq = 0.f;
      #pragma unroll
      for (int m=0;m<16;m++){ ss += redS[m][t]; qq += redQ[m][t]; }
      ps[(size_t)(pblk0 + blockIdx.x)*HH + n0 + t] = ss;
      pq[(size_t)(pblk0 + blockIdx.x)*HH + n0 + t] = qq;
    }
    return;
  }

  const bool fullc = (n0 + 128 <= N);
  #pragma unroll
  for (int i=0;i<8;i++){
    int gm = m0 + tm*8 + i;
    if (gm < Mrows){
      if (fullc){
        float v[8];
        #pragma unroll
        for (int j2=0;j2<8;j2++){
          int gn = n0 + tn*8 + j2;
          float val = acc[i][j2] + bias[gn];
          if (MODE == 1) val = fmaxf(val, 0.f);
          v[j2] = val;
        }
        float* cp = &Co[(long long)gm*ldc + n0 + tn*8];
        if (MODE == 2){
          float4 o0 = *(float4*)cp, o1 = *(float4*)(cp+4);
          v[0]+=o0.x; v[1]+=o0.y; v[2]+=o0.z; v[3]+=o0.w;
          v[4]+=o1.x; v[5]+=o1.y; v[6]+=o1.z; v[7]+=o1.w;
        }
        *(float4*)cp     = make_float4(v[0],v[1],v[2],v[3]);
        *(float4*)(cp+4) = make_float4(v[4],v[5],v[6],v[7]);
      } else {
        #pragma unroll
        for (int j2=0;j2<8;j2++){
          int gn = n0 + tn*8 + j2;
          if (gn < N){
            long long oi = (long long)gm*ldc + gn;
            float val = acc[i][j2] + bias[gn];
            if (MODE == 1) val = fmaxf(val, 0.f);
            if (MODE == 2) val += Co[oi];
            Co[oi] = val;
          }
        }
      }
    }
  }
}

// ---------------------------------------------------------------------------
// Dual-output small-K GEMM (S1 fusion): res + relu(out1) in one dispatch.
// ---------------------------------------------------------------------------
__global__ void gemm_tn_dual2(const float* __restrict__ Xb, long long r0,
                              const float* __restrict__ W1, const float* __restrict__ b1,
                              float* __restrict__ Co1,
                              const float* __restrict__ A2, const float* __restrict__ W2,
                              const float* __restrict__ b2, float* __restrict__ Co2,
                              int Mrows)
{
  __shared__ __align__(16) float As1[32][132];
  __shared__ __align__(16) float As2[32][132];
  __shared__ __align__(16) float Ws1[32][132];
  __shared__ __align__(16) float Ws2[32][132];
  const int m0 = blockIdx.x*128, n0 = blockIdx.y*128;
  const int t  = threadIdx.x;
  const int tm = t >> 4, tn = t & 15;
  float acc1[8][8], acc2[8][8];
  #pragma unroll
  for (int i=0;i<8;i++)
    #pragma unroll
    for (int j2=0;j2<8;j2++){ acc1[i][j2] = 0.f; acc2[i][j2] = 0.f; }

  for (int k0=0;k0<CC;k0+=32){
    #pragma unroll
    for (int u=0;u<16;u++){
      int idx = u*256 + t;
      int r = idx >> 5, c = idx & 31;
      int gk = k0 + c;
      float a1=0.f, a2=0.f, w1=0.f, w2=0.f;
      if (gk < CC){
        int gm = m0 + r;
        if (gm < Mrows){
          long long gr = r0 + gm;
          a1 = Xb[gr*II + gk];
          a2 = A2[(long long)gm*CC + gk];
        }
        int gn = n0 + r;
        w1 = W1[(long long)gn*CC + gk];
        w2 = W2[(long long)gn*CC + gk];
      }
      As1[c][r] = a1; As2[c][r] = a2;
      Ws1[c][r] = w1; Ws2[c][r] = w2;
    }
    __syncthreads();
    #pragma unroll
    for (int kk=0;kk<32;kk++){
      const float4 p0 = *(const float4*)&As1[kk][tm*8];
      const float4 p1 = *(const float4*)&As1[kk][tm*8+4];
      const float4 q0 = *(const float4*)&As2[kk][tm*8];
      const float4 q1 = *(const float4*)&As2[kk][tm*8+4];
      const float4 u0 = *(const float4*)&Ws1[kk][tn*8];
      const float4 u1 = *(const float4*)&Ws1[kk][tn*8+4];
      const float4 v0 = *(const float4*)&Ws2[kk][tn*8];
      const float4 v1 = *(const float4*)&Ws2[kk][tn*8+4];
      const float a1v[8] = {p0.x,p0.y,p0.z,p0.w,p1.x,p1.y,p1.z,p1.w};
      const float a2v[8] = {q0.x,q0.y,q0.z,q0.w,q1.x,q1.y,q1.z,q1.w};
      const float w1v[8] = {u0.x,u0.y,u0.z,u0.w,u1.x,u1.y,u1.z,u1.w};
      const float w2v[8] = {v0.x,v0.y,v0.z,v0.w,v1.x,v1.y,v1.z,v1.w};
      #pragma unroll
      for (int i=0;i<8;i++)
        #pragma unroll
        for (int j2=0;j2<8;j2++){
          acc1[i][j2] = fmaf(a1v[i], w1v[j2], acc1[i][j2]);
          acc2[i][j2] = fmaf(a2v[i], w2v[j2], acc2[i][j2]);
        }
    }
    __syncthreads();
  }
  #pragma unroll
  for (int i=0;i<8;i++){
    int gm = m0 + tm*8 + i;
    if (gm < Mrows){
      float v1[8], v2[8];
      #pragma unroll
      for (int j2=0;j2<8;j2++){
        int gn = n0 + tn*8 + j2;
        v1[j2] = acc1[i][j2] + b1[gn];
        v2[j2] = fmaxf(acc2[i][j2] + b2[gn], 0.f);
      }
      float* c1 = &Co1[(long long)gm*HH + n0 + tn*8];
      float* c2 = &Co2[(long long)gm*HH + n0 + tn*8];
      *(float4*)c1     = make_float4(v1[0],v1[1],v1[2],v1[3]);
      *(float4*)(c1+4) = make_float4(v1[4],v1[5],v1[6],v1[7]);
      *(float4*)c2     = make_float4(v2[0],v2[1],v2[2],v2[3]);
      *(float4*)(c2+4) = make_float4(v2[4],v2[5],v2[6],v2[7]);
    }
  }
}

// ---------------------------------------------------------------------------
// FUSED pass-B kernel (R13): per 128-row block, recompute out1r from the Xc
// tile IN-KERNEL (ascending-k fmaf == gemm_tn's accumulation order -> bit-
// identical values), split to bf16 A-staging, run conv2 MFMA over K=256,
// emit BN2 stats. Eliminates the 67MB SA2 scratch (589MB/dispatch measured
// HBM traffic, 5x write-amplified). Grid (SB/128, 2): y = conv2 col-half.
// ---------------------------------------------------------------------------
__global__ __launch_bounds__(256) void conv2stats_k(
    const float* __restrict__ Xc,      // SB x 40
    const float* __restrict__ W1F,     // 256 x 40 (folded conv1)
    const float* __restrict__ B1F,     // 256
    const unsigned short* __restrict__ Wh, const unsigned short* __restrict__ Wl, // conv2 split
    const float* __restrict__ bias,    // conv2_b
    float* __restrict__ ps, float* __restrict__ pq)
{
  __shared__ __align__(16) float Xs[40][132];
  __shared__ __align__(16) unsigned short Ah[128*32];
  __shared__ __align__(16) unsigned short Al[128*32];
  __shared__ __align__(16) unsigned short Bh[128*32];
  __shared__ __align__(16) unsigned short Bl[128*32];
  const int t = threadIdx.x;
  const int m0 = blockIdx.x*128, n0 = blockIdx.y*128;
  const int lane = t & 63, w = t >> 6;
  const int wm = (w & 1)*64, wn = (w >> 1)*64;
  const int fr = lane & 15, fg = lane >> 4;

  // stage Xc tile: rows [m0, m0+128), cols 0..40 -> Xs[k][r]
  for (int idx = t; idx < 128*CC; idx += 256){
    int r = idx / CC, k = idx - r*CC;
    Xs[k][r] = Xc[(size_t)(m0 + r)*CC + k];
  }
  __syncthreads();

  f32x4 acc[4][4];
  #pragma unroll
  for (int i=0;i<4;i++)
    #pragma unroll
    for (int j=0;j<4;j++){ f32x4 z; z[0]=0;z[1]=0;z[2]=0;z[3]=0; acc[i][j]=z; }

  for (int k0=0; k0<HH; k0+=32){
    // ---- compute out1r cols [k0,k0+32) for all 128 rows; stage split bf16 ----
    #pragma unroll
    for (int cc=0; cc<2; cc++){
      const int c   = t + cc*256;
      const int row = c >> 2, kg = c & 3;
      float v[8];
      #pragma unroll
      for (int e=0;e<8;e++){
        const int col = k0 + kg*8 + e;
        const float* wp = W1F + (size_t)col*CC;
        float a = 0.f;
        #pragma unroll
        for (int k=0;k<CC;k++) a = fmaf(Xs[k][row], wp[k], a);
        v[e] = fmaxf(a + B1F[col], 0.f);
      }
      bf16x8 hi, lo; cvt8(v, hi, lo);
      const int byte = row*64 + ((kg*16) ^ (((row>>1)&3)<<4));
      *(bf16x8*)((char*)Ah + byte) = hi;
      *(bf16x8*)((char*)Al + byte) = lo;
      const size_t off = (size_t)(n0+row)*HH + k0 + kg*8;
      *(bf16x8*)((char*)Bh + byte) = *(const bf16x8*)&Wh[off];
      *(bf16x8*)((char*)Bl + byte) = *(const bf16x8*)&Wl[off];
    }
    __syncthreads();
    // ---- MFMA step (same structure as gemm_mfp) ----
    bf16x8 ahi[4], alo[4], bhi[4], blo[4];
    #pragma unroll
    for (int mt=0; mt<4; mt++){
      const int r = wm + mt*16 + fr;
      const int byte = r*64 + ((fg*16) ^ (((r>>1)&3)<<4));
      ahi[mt] = *(const bf16x8*)((const char*)Ah + byte);
      alo[mt] = *(const bf16x8*)((const char*)Al + byte);
    }
    #pragma unroll
    for (int nt=0; nt<4; nt++){
      const int r = wn + nt*16 + fr;
      const int byte = r*64 + ((fg*16) ^ (((r>>1)&3)<<4));
      bhi[nt] = *(const bf16x8*)((const char*)Bh + byte);
      blo[nt] = *(const bf16x8*)((const char*)Bl + byte);
    }
    #pragma unroll
    for (int mt=0; mt<4; mt++)
      #pragma unroll
      for (int nt=0; nt<4; nt++){
        acc[mt][nt] = __builtin_amdgcn_mfma_f32_16x16x32_bf16(alo[mt], bhi[nt], acc[mt][nt], 0,0,0);
        acc[mt][nt] = __builtin_amdgcn_mfma_f32_16x16x32_bf16(ahi[mt], blo[nt], acc[mt][nt], 0,0,0);
        acc[mt][nt] = __builtin_amdgcn_mfma_f32_16x16x32_bf16(ahi[mt], bhi[nt], acc[mt][nt], 0,0,0);
      }
    __syncthreads();
  }

  // ---- BN2 stats epilogue (identical to gemm_mfp MODE 3) ----
  __shared__ float swS[4][4][16];
  __shared__ float qwS[4][4][16];
  float sv[4], qv[4];
  #pragma unroll
  for (int nt=0; nt<4; nt++){
    const int col = n0 + wn + nt*16 + fr;
    const float bv = bias[col];
    float s = 0.f, q = 0.f;
    #pragma unroll
    for (int mt=0; mt<4; mt++)
      #pragma unroll
      for (int i=0;i<4;i++){
        const float val = acc[mt][nt][i] + bv;
        s += val; q = fmaf(val, val, q);
      }
    s += __shfl_down(s, 32); q += __shfl_down(q, 32);
    s += __shfl_down(s, 16); q += __shfl_down(q, 16);
    sv[nt] = s; qv[nt] = q;
  }
  if (fg == 0){
    #pragma unroll
    for (int nt=0; nt<4; nt++){ swS[w][nt][fr] = sv[nt]; qwS[w][nt][fr] = qv[nt]; }
  }
  __syncthreads();
  if ((w & 1) == 0 && lane < 16){
    #pragma unroll
    for (int nt=0; nt<4; nt++){
      const int col = n0 + wn + nt*16 + fr;
      ps[(size_t)blockIdx.x*HH + col] = swS[w][nt][fr] + swS[w+1][nt][fr];
      pq[(size_t)blockIdx.x*HH + col] = qwS[w][nt][fr] + qwS[w+1][nt][fr];
    }
  }
}

// ---------------------------------------------------------------------------
// Split-bf16 MFMA GEMM with PRE-SPLIT B. MODE 0: store; 2: accumulate.
// ---------------------------------------------------------------------------
template<int MODE>
__global__ __launch_bounds__(256) void gemm_mfp(
    const float* __restrict__ A, int lda,
    const unsigned short* __restrict__ Wh, const unsigned short* __restrict__ Wl, int ldw,
    const float* __restrict__ bias,
    float* __restrict__ Co, int ldc,
    int N, int K)
{
  __shared__ __align__(16) unsigned short Ah[128*32];
  __shared__ __align__(16) unsigned short Al[128*32];
  __shared__ __align__(16) unsigned short Bh[128*32];
  __shared__ __align__(16) unsigned short Bl[128*32];
  const int t = threadIdx.x;
  const int m0 = blockIdx.x*128, n0 = blockIdx.y*128;
  const int lane = t & 63, w = t >> 6;
  const int wm = (w & 1)*64, wn = (w >> 1)*64;
  const int fr = lane & 15, fg = lane >> 4;

  f32x4 acc[4][4];
  #pragma unroll
  for (int i=0;i<4;i++)
    #pragma unroll
    for (int j=0;j<4;j++){ f32x4 z; z[0]=0;z[1]=0;z[2]=0;z[3]=0; acc[i][j]=z; }

  for (int k0=0; k0<K; k0+=32){
    #pragma unroll
    for (int cc=0; cc<2; cc++){
      const int c   = t + cc*256;
      const int row = c >> 2, kg = c & 3;
      const int byte = row*64 + ((kg*16) ^ (((row>>1)&3)<<4));
      {
        const float* ap = A + (size_t)(m0+row)*lda + k0 + kg*8;
        float v[8];
        *(float4*)&v[0] = *(const float4*)ap;
        *(float4*)&v[4] = *(const float4*)(ap+4);
        bf16x8 hi, lo; cvt8(v, hi, lo);
        *(bf16x8*)((char*)Ah + byte) = hi;
        *(bf16x8*)((char*)Al + byte) = lo;
      }
      {
        const size_t off = (size_t)(n0+row)*ldw + k0 + kg*8;
        *(bf16x8*)((char*)Bh + byte) = *(const bf16x8*)&Wh[off];
        *(bf16x8*)((char*)Bl + byte) = *(const bf16x8*)&Wl[off];
      }
    }
    __syncthreads();
    bf16x8 ahi[4], alo[4], bhi[4], blo[4];
    #pragma unroll
    for (int mt=0; mt<4; mt++){
      const int r = wm + mt*16 + fr;
      const int byte = r*64 + ((fg*16) ^ (((r>>1)&3)<<4));
      ahi[mt] = *(const bf16x8*)((const char*)Ah + byte);
      alo[mt] = *(const bf16x8*)((const char*)Al + byte);
    }
    #pragma unroll
    for (int nt=0; nt<4; nt++){
      const int r = wn + nt*16 + fr;
      const int byte = r*64 + ((fg*16) ^ (((r>>1)&3)<<4));
      bhi[nt] = *(const bf16x8*)((const char*)Bh + byte);
      blo[nt] = *(const bf16x8*)((const char*)Bl + byte);
    }
    #pragma unroll
    for (int mt=0; mt<4; mt++)
      #pragma unroll
      for (int nt=0; nt<4; nt++){
        acc[mt][nt] = __builtin_amdgcn_mfma_f32_16x16x32_bf16(alo[mt], bhi[nt], acc[mt][nt], 0,0,0);
        acc[mt][nt] = __builtin_amdgcn_mfma_f32_16x16x32_bf16(ahi[mt], blo[nt], acc[mt][nt], 0,0,0);
        acc[mt][nt] = __builtin_amdgcn_mfma_f32_16x16x32_bf16(ahi[mt], bhi[nt], acc[mt][nt], 0,0,0);
      }
    __syncthreads();
  }

  #pragma unroll
  for (int mt=0; mt<4; mt++){
    #pragma unroll
    for (int nt=0; nt<4; nt++){
      const int col = n0 + wn + nt*16 + fr;
      const float bv = bias[col];
      #pragma unroll
      for (int i=0;i<4;i++){
        const int row = m0 + wm + mt*16 + fg*4 + i;
        const size_t oi = (size_t)row*ldc + col;
        float val = acc[mt][nt][i] + bv;
        if (MODE == 2) val += Co[oi];
        Co[oi] = val;
      }
    }
  }
}

// ---------------------------------------------------------------------------
// Dual-A fused out-projection GEMM with pre-split B (cw).
// ---------------------------------------------------------------------------
__global__ __launch_bounds__(256) void gemm_mfp_dual(
    const float* __restrict__ A1, const float* __restrict__ A2,
    const unsigned short* __restrict__ Wh, const unsigned short* __restrict__ Wl,
    const float* __restrict__ bias,
    float* __restrict__ Co, int ldc, int N)
{
  __shared__ __align__(16) unsigned short Ah[128*32];
  __shared__ __align__(16) unsigned short Al[128*32];
  __shared__ __align__(16) unsigned short Bh[128*32];
  __shared__ __align__(16) unsigned short Bl[128*32];
  const int t = threadIdx.x;
  const int m0 = blockIdx.x*128, n0 = blockIdx.y*128;
  const int lane = t & 63, w = t >> 6;
  const int wm = (w & 1)*64, wn = (w >> 1)*64;
  const int fr = lane & 15, fg = lane >> 4;

  f32x4 acc[4][4];
  #pragma unroll
  for (int i=0;i<4;i++)
    #pragma unroll
    for (int j=0;j<4;j++){ f32x4 z; z[0]=0;z[1]=0;z[2]=0;z[3]=0; acc[i][j]=z; }

  for (int k0=0; k0<2*HH; k0+=32){
    const float* Abase = (k0 < HH) ? A1 : A2;
    const int    kofs  = (k0 < HH) ? k0 : (k0 - HH);
    #pragma unroll
    for (int cc=0; cc<2; cc++){
      const int c   = t + cc*256;
      const int row = c >> 2, kg = c & 3;
      const int byte = row*64 + ((kg*16) ^ (((row>>1)&3)<<4));
      {
        const float* ap = Abase + (size_t)(m0+row)*HH + kofs + kg*8;
        float v[8];
        *(float4*)&v[0] = *(const float4*)ap;
        *(float4*)&v[4] = *(const float4*)(ap+4);
        bf16x8 hi, lo; cvt8(v, hi, lo);
        *(bf16x8*)((char*)Ah + byte) = hi;
        *(bf16x8*)((char*)Al + byte) = lo;
      }
      {
        const size_t off = (size_t)(n0+row)*(2*HH) + k0 + kg*8;
        *(bf16x8*)((char*)Bh + byte) = *(const bf16x8*)&Wh[off];
        *(bf16x8*)((char*)Bl + byte) = *(const bf16x8*)&Wl[off];
      }
    }
    __syncthreads();
    bf16x8 ahi[4], alo[4], bhi[4], blo[4];
    #pragma unroll
    for (int mt=0; mt<4; mt++){
      const int r = wm + mt*16 + fr;
      const int byte = r*64 + ((fg*16) ^ (((r>>1)&3)<<4));
      ahi[mt] = *(const bf16x8*)((const char*)Ah + byte);
      alo[mt] = *(const bf16x8*)((const char*)Al + byte);
    }
    #pragma unroll
    for (int nt=0; nt<4; nt++){
      const int r = wn + nt*16 + fr;
      const int byte = r*64 + ((fg*16) ^ (((r>>1)&3)<<4));
      bhi[nt] = *(const bf16x8*)((const char*)Bh + byte);
      blo[nt] = *(const bf16x8*)((const char*)Bl + byte);
    }
    #pragma unroll
    for (int mt=0; mt<4; mt++)
      #pragma unroll
      for (int nt=0; nt<4; nt++){
        acc[mt][nt] = __builtin_amdgcn_mfma_f32_16x16x32_bf16(alo[mt], bhi[nt], acc[mt][nt], 0,0,0);
        acc[mt][nt] = __builtin_amdgcn_mfma_f32_16x16x32_bf16(ahi[mt], blo[nt], acc[mt][nt], 0,0,0);
        acc[mt][nt] = __builtin_amdgcn_mfma_f32_16x16x32_bf16(ahi[mt], bhi[nt], acc[mt][nt], 0,0,0);
      }
    __syncthreads();
  }

  #pragma unroll
  for (int mt=0; mt<4; mt++){
    #pragma unroll
    for (int nt=0; nt<4; nt++){
      const int col = n0 + wn + nt*16 + fr;
      const float bv = bias[col];
      #pragma unroll
      for (int i=0;i<4;i++){
        const int row = m0 + wm + mt*16 + fg*4 + i;
        const size_t oi = (size_t)row*ldc + col;
        Co[oi] = acc[mt][nt][i] + bv;
      }
    }
  }
}

// ---------------------------------------------------------------------------
// BN final — parallel (R12, proven) + fold
// ---------------------------------------------------------------------------
__global__ void bn_final_k(const float* __restrict__ ps, const float* __restrict__ pq,
                           const float* __restrict__ g, const float* __restrict__ b,
                           float* __restrict__ sc, float* __restrict__ sh, int npart){
  const int col = blockIdx.x;
  const int t = threadIdx.x;
  double s = 0.0, q = 0.0;
  for (int i=t; i<npart; i+=256){
    s += (double)ps[(size_t)i*HH + col];
    q += (double)pq[(size_t)i*HH + col];
  }
  __shared__ double sd[256], qd[256];
  sd[t] = s; qd[t] = q;
  __syncthreads();
  for (int o=128;o>0;o>>=1){
    if (t < o){ sd[t] += sd[t+o]; qd[t] += qd[t+o]; }
    __syncthreads();
  }
  if (t == 0){
    double mu  = sd[0] / (double)SB;
    double var = qd[0] / (double)SB - mu*mu;
    float scv = (float)((double)g[col] / sqrt(var + 1e-5));
    sc[col] = scv;
    sh[col] = (float)((double)b[col] - mu*(double)scv);
  }
}

__global__ void fold_k(const float* __restrict__ w, const float* __restrict__ b,
                       const float* __restrict__ sc, const float* __restrict__ sh,
                       float* __restrict__ wf, float* __restrict__ bf, int K){
  int idx = blockIdx.x*blockDim.x + threadIdx.x;
  if (idx < 256*K){ int o = idx / K; wf[idx] = w[idx]*sc[o]; }
  if (idx < 256)  bf[idx] = b[idx]*sc[idx] + sh[idx];
}

// ---------------------------------------------------------------------------
// LayerNorm over last dim (256), out-of-place. One block per row.
// ---------------------------------------------------------------------------
__global__ void ln_rows_k(const float* __restrict__ Xi, float* __restrict__ Xo,
                          const float* __restrict__ g, const float* __restrict__ b){
  long long row = blockIdx.x;
  int t = threadIdx.x;
  float v = Xi[row*HH + t];
  float s = v, q = v*v;
  #pragma unroll
  for (int o=32;o>0;o>>=1){ s += __shfl_down(s,o); q += __shfl_down(q,o); }
  __shared__ float ssm[4], qqm[4];
  int w = t >> 6;
  if ((t & 63) == 0){ ssm[w] = s; qqm[w] = q; }
  __syncthreads();
  if (t == 0){ ssm[0] = ssm[0]+ssm[1]+ssm[2]+ssm[3]; qqm[0] = qqm[0]+qqm[1]+qqm[2]+qqm[3]; }
  __syncthreads();
  s = ssm[0]; q = qqm[0];
  float mu  = s * (1.f/HH);
  float var = q * (1.f/HH) - mu*mu;
  float rs  = rsqrtf(var + EPSF);
  Xo[row*HH + t] = (v - mu)*rs*g[t] + b[t];
}

// ---------------------------------------------------------------------------
// FUSED dual-GRU gate scan — MFMA edition (R10, proven).
// ---------------------------------------------------------------------------
__global__ __launch_bounds__(512) void gru_scan_mfma_k(
  const float* __restrict__ gi1, const unsigned short* __restrict__ wf1,
  const float* __restrict__ b1v, const float* __restrict__ m1v,
  float* __restrict__ hc1, float* __restrict__ Hh1o, int nst1,
  const float* __restrict__ gi2, const unsigned short* __restrict__ wf2,
  const float* __restrict__ b2v, const float* __restrict__ m2v,
  float* __restrict__ hc2, float* __restrict__ Hh2o, int nst2)
{
  const int gsel = blockIdx.x & 1;
  const int blk  = blockIdx.x >> 1;
  const float* gi    = gsel ? gi2 : gi1;
  const unsigned short* wfr = gsel ? wf2 : wf1;
  const float* bhh   = gsel ? b2v : b1v;
  const float* mask0 = gsel ? m2v : m1v;
  float* hcar        = gsel ? hc2 : hc1;
  float* Hh          = gsel ? Hh2o : Hh1o;
  const int nst      = gsel ? nst2 : nst1;
  if (nst <= 0) return;

  const int t    = threadIdx.x;
  const int b0   = blk*4;
  const int lane = t & 63, wid = t >> 6;      // 8 waves
  const int arow = lane & 15, kg = lane >> 4; // A-fragment coords
  const bool act = (arow < 4);
  const int uj = t & 255, ur = t >> 8;        // gate coords: rows ur, ur+2

  __shared__ __align__(16) unsigned short AhS[4][256];
  __shared__ __align__(16) unsigned short AlS[4][256];
  __shared__ __align__(16) float ghS[4][768];
  __shared__ float mkz[4];

  float hold0 = hcar[(size_t)(b0+ur  )*HH + uj];
  float hold1 = hcar[(size_t)(b0+ur+2)*HH + uj];
  const float br = bhh[uj], bz = bhh[uj+HH], bn_ = bhh[uj+2*HH];

  {
    unsigned short hb0 = f2bf_rne(hold0);
    AhS[ur  ][uj] = hb0;  AlS[ur  ][uj] = f2bf_rne(hold0 - bf2f(hb0));
    unsigned short hb1 = f2bf_rne(hold1);
    AhS[ur+2][uj] = hb1;  AlS[ur+2][uj] = f2bf_rne(hold1 - bf2f(hb1));
  }
  __syncthreads();

  const unsigned short* wfbase = wfr + (((size_t)(wid*6)*8)*64 + lane)*8;

  for (int st=0; st<nst; ++st){
    const size_t ga = ((size_t)st*BB + b0 + ur  )*G3 + uj;
    const size_t gb = ((size_t)st*BB + b0 + ur+2)*G3 + uj;
    const float i0r=gi[ga], i0z=gi[ga+HH], i0n=gi[ga+2*HH];
    const float i1r=gi[gb], i1z=gi[gb+HH], i1n=gi[gb+2*HH];
    if (t < 4) mkz[t] = mask0[(size_t)st*BB + b0 + t];

    bf16x8 AH[8], AL[8];
    #pragma unroll
    for (int kt=0; kt<8; kt++){
      if (act){
        AH[kt] = *(const bf16x8*)&AhS[arow][kt*32 + kg*8];
        AL[kt] = *(const bf16x8*)&AlS[arow][kt*32 + kg*8];
      } else {
        bf16x8 z = {0,0,0,0,0,0,0,0};
        AH[kt] = z; AL[kt] = z;
      }
    }
    #pragma unroll
    for (int nt=0; nt<6; nt++){
      const unsigned short* wp = wfbase + (size_t)nt*8*64*8;
      f32x4 acc = {0.f,0.f,0.f,0.f};
      #pragma unroll
      for (int kt=0; kt<8; kt++){
        const bf16x8 b = *(const bf16x8*)(wp + (size_t)kt*64*8);
        acc = __builtin_amdgcn_mfma_f32_16x16x32_bf16(AL[kt], b, acc, 0,0,0);
        acc = __builtin_amdgcn_mfma_f32_16x16x32_bf16(AH[kt], b, acc, 0,0,0);
      }
      if (lane < 16){
        const int col = (wid*6 + nt)*16 + lane;
        ghS[0][col] = acc[0];
        ghS[1][col] = acc[1];
        ghS[2][col] = acc[2];
        ghS[3][col] = acc[3];
      }
    }
    __syncthreads();

    {
      const float ar = ghS[ur][uj]       + br;
      const float az = ghS[ur][uj+HH]    + bz;
      const float an = ghS[ur][uj+2*HH]  + bn_;
      const float rr = 1.f/(1.f + __expf(-(i0r + ar)));
      const float zz = 1.f/(1.f + __expf(-(i0z + az)));
      const float nn = tanhf(fmaf(rr, an, i0n));
      const float m  = mkz[ur];
      const float hnew = (1.f - zz)*nn + zz*hold0;
      const float hv = hnew*m + hold0*(1.f - m);
      hold0 = hv;
      unsigned short hb = f2bf_rne(hv);
      AhS[ur][uj] = hb; AlS[ur][uj] = f2bf_rne(hv - bf2f(hb));
      Hh[((size_t)st*BB + b0 + ur)*HH + uj] = hv;
    }
    {
      const int r_ = ur + 2;
      const float ar = ghS[r_][uj]       + br;
      const float az = ghS[r_][uj+HH]    + bz;
      const float an = ghS[r_][uj+2*HH]  + bn_;
      const float rr = 1.f/(1.f + __expf(-(i1r + ar)));
      const float zz = 1.f/(1.f + __expf(-(i1z + az)));
      const float nn = tanhf(fmaf(rr, an, i1n));
      const float m  = mkz[r_];
      const float hnew = (1.f - zz)*nn + zz*hold1;
      const float hv = hnew*m + hold1*(1.f - m);
      hold1 = hv;
      unsigned short hb = f2bf_rne(hv);
      AhS[r_][uj] = hb; AlS[r_][uj] = f2bf_rne(hv - bf2f(hb));
      Hh[((size_t)st*BB + b0 + r_)*HH + uj] = hv;
    }
    __syncthreads();
  }
  hcar[(size_t)(b0+ur  )*HH + uj] = hold0;
  hcar[(size_t)(b0+ur+2)*HH + uj] = hold1;
}

// ---------------------------------------------------------------------------
// Head (fused LN2): x=LN2(row); relu(x@nn1.T+b1) -> LN(8) -> @nn2.T+b2.
// ---------------------------------------------------------------------------
__global__ void head_ln_k(const float* __restrict__ hx,
                          const float* __restrict__ g2, const float* __restrict__ b2,
                          const float* __restrict__ w1, const float* __restrict__ b1,
                          const float* __restrict__ g3, const float* __restrict__ b3,
                          const float* __restrict__ w2, const float* __restrict__ b2h,
                          float* __restrict__ outp, long long r0){
  long long row = blockIdx.x;
  int t = threadIdx.x;
  float v = hx[row*HH + t];
  float s = v, q = v*v;
  #pragma unroll
  for (int o=32;o>0;o>>=1){ s += __shfl_down(s,o); q += __shfl_down(q,o); }
  __shared__ float ssm[4], qqm[4];
  int w = t >> 6;
  if ((t & 63) == 0){ ssm[w] = s; qqm[w] = q; }
  __syncthreads();
  if (t == 0){ ssm[0] = ssm[0]+ssm[1]+ssm[2]+ssm[3]; qqm[0] = qqm[0]+qqm[1]+qqm[2]+qqm[3]; }
  __syncthreads();
  s = ssm[0]; q = qqm[0];
  float mu  = s * (1.f/HH);
  float var = q * (1.f/HH) - mu*mu;
  float rs  = rsqrtf(var + EPSF);
  __shared__ float xs[HH];
  xs[t] = (v - mu)*rs*g2[t] + b2[t];
  __syncthreads();
  int o = t >> 5, l = t & 31;
  const float* wv = w1 + o*HH;
  float acc = 0.f;
  for (int k=l;k<HH;k+=32) acc = fmaf(xs[k], wv[k], acc);
  #pragma unroll
  for (int d=16;d>0;d>>=1) acc += __shfl_down(acc, d, 32);
  __shared__ float a8[8];
  if (l == 0) a8[o] = fmaxf(acc + b1[o], 0.f);
  __syncthreads();
  if (t == 0){
    float ss = 0.f;
    #pragma unroll
    for (int i=0;i<8;i++) ss += a8[i];
    float m8 = ss*0.125f;
    float qq = 0.f;
    #pragma unroll
    for (int i=0;i<8;i++){ float d = a8[i]-m8; qq = fmaf(d,d,qq); }
    float r8 = rsqrtf(qq*0.125f + EPSF);
    float y0 = b2h[0], y1 = b2h[1];
    #pragma unroll
    for (int i=0;i<8;i++){
      float vv = (a8[i]-m8)*r8*g3[i] + b3[i];
      y0 = fmaf(vv, w2[i],   y0);
      y1 = fmaf(vv, w2[8+i], y1);
    }
    outp[(r0+row)*2+0] = y0; outp[(r0+row)*2+1] = y1;
  }
}

// ---------------------------------------------------------------------------
// Host launcher. R13 = R12 + pass-B fully fused (conv2stats_k recomputes
// out1r in-kernel; SA2 scratch eliminated).
// ---------------------------------------------------------------------------
extern "C" void kernel_launch(void* const* d_in, const int* in_sizes, int n_in,
                              void* d_out, int out_size, void* d_ws, size_t ws_size,
                              hipStream_t stream) {
  const float* X      = (const float*)d_in[0];
  const float* Mi     = (const float*)d_in[1];
  const float* mask   = (const float*)d_in[2];
  const float* i2h_w  = (const float*)d_in[3];
  const float* i2h_b  = (const float*)d_in[4];
  const float* comb_w = (const float*)d_in[5];
  const float* comb_b = (const float*)d_in[6];
  const float* down_w = (const float*)d_in[7];
  const float* down_b = (const float*)d_in[8];
  const float* conv1_w= (const float*)d_in[9];
  const float* conv1_b= (const float*)d_in[10];
  const float* conv2_w= (const float*)d_in[11];
  const float* conv2_b= (const float*)d_in[12];
  const float* bn1_g  = (const float*)d_in[13];
  const float* bn1_b  = (const float*)d_in[14];
  const float* bn2_g  = (const float*)d_in[15];
  const float* bn2_b  = (const float*)d_in[16];
  const float* r1_wih = (const float*)d_in[17];
  const float* r1_whh = (const float*)d_in[18];
  const float* r1_bih = (const float*)d_in[19];
  const float* r1_bhh = (const float*)d_in[20];
  const float* r1_cw  = (const float*)d_in[21];
  const float* r1_cb  = (const float*)d_in[22];
  const float* r2_wih = (const float*)d_in[23];
  const float* r2_whh = (const float*)d_in[24];
  const float* r2_bih = (const float*)d_in[25];
  const float* r2_bhh = (const float*)d_in[26];
  const float* r2_cw  = (const float*)d_in[27];
  const float* r2_cb  = (const float*)d_in[28];
  const float* ln1_g  = (const float*)d_in[29];
  const float* ln1_b  = (const float*)d_in[30];
  const float* ln2_g  = (const float*)d_in[31];
  const float* ln2_b  = (const float*)d_in[32];
  const float* ln3_g  = (const float*)d_in[33];
  const float* ln3_b  = (const float*)d_in[34];
  const float* nn1_w  = (const float*)d_in[35];
  const float* nn1_b  = (const float*)d_in[36];
  const float* nn2_w  = (const float*)d_in[37];
  const float* nn2_b  = (const float*)d_in[38];
  float* outp = (float*)d_out;

  const size_t us_elems = 2*((size_t)HH*HH + (size_t)HH*HH + (size_t)G3*HH
                           + (size_t)G3*HH + (size_t)HH*2*HH + (size_t)HH*2*HH)
                        + 2*(size_t)G3*HH;   // WF1/WF2
  const size_t tail_floats = 2*(size_t)BB*HH + 2*(size_t)NPART*HH + 2*HH
                           + (size_t)256*40 + 256 + (size_t)HH*HH + 256
                           + (size_t)SB*CC
                           + (us_elems + 1)/2;
  int cands[6] = {256,128,64,32,16,8};
  int sc_chunk = 0;
  for (int ci=0; ci<6; ci++){
    size_t R = (size_t)512*cands[ci];
    size_t need = (R*2560 + tail_floats)*sizeof(float);
    if (need <= ws_size){ sc_chunk = cands[ci]; break; }
  }
  if (!sc_chunk) return;

  const size_t R = (size_t)512*sc_chunk;     // rows per chunk
  const int Ri = (int)R;
  const int nchunks = SB / Ri;

  float* wsf = (float*)d_ws;
  float* A   = wsf;                    // R*256  (res -> hx)
  float* GI1 = A + R*HH;               // R*768  gi for GRU1(c)
  float* Cxp = GI1;                    // ALIAS: GI1 dead after scan; Cxp lives after
  float* GI2 = GI1 + R*G3;             // R*768  gi for GRU2(c)
  float* Ee  = GI2 + R*G3;             // R*256  out1r -> Hh1
  float* Hh2 = Ee + R*HH;              // R*256  Hh of GRU2(c-1)
  float* Hx1 = Hh2 + R*HH;             // R*256  hx1(c) = LN1 out
  float* tl  = Hx1 + R*HH;
  float* H1C = tl;                     // BB*HH
  float* H2C = H1C + (size_t)BB*HH;
  float* PS  = H2C + (size_t)BB*HH;    // NPART*HH (capacity)
  float* PQ  = PS  + (size_t)NPART*HH;
  float* SCv = PQ  + (size_t)NPART*HH; // HH
  float* SHv = SCv + HH;
  float* W1F = SHv + HH;               // 256*40
  float* B1F = W1F + (size_t)256*40;   // 256
  float* W2F = B1F + HH;               // 256*256
  float* B2F = W2F + (size_t)HH*HH;    // 256
  float* XcF = B2F + HH;               // SB*40 persisted comb output
  unsigned short* usb = (unsigned short*)(XcF + (size_t)SB*CC);
  unsigned short* C2H  = usb;                       // conv2_w raw split (HH*HH)
  unsigned short* C2L  = C2H  + (size_t)HH*HH;
  unsigned short* W2FH = C2L  + (size_t)HH*HH;      // folded conv2 (HH*HH)
  unsigned short* W2FL = W2FH + (size_t)HH*HH;
  unsigned short* WI1H = W2FL + (size_t)HH*HH;      // r1_wih (G3*HH)
  unsigned short* WI1L = WI1H + (size_t)G3*HH;
  unsigned short* WI2H = WI1L + (size_t)G3*HH;      // r2_wih (G3*HH)
  unsigned short* WI2L = WI2H + (size_t)G3*HH;
  unsigned short* CW1H = WI2L + (size_t)G3*HH;      // r1_cw (HH*2HH)
  unsigned short* CW1L = CW1H + (size_t)HH*2*HH;
  unsigned short* CW2H = CW1L + (size_t)HH*2*HH;    // r2_cw (HH*2HH)
  unsigned short* CW2L = CW2H + (size_t)HH*2*HH;
  unsigned short* WF1  = CW2L + (size_t)HH*2*HH;    // whh MFMA frags (GRU1)
  unsigned short* WF2  = WF1 + (size_t)G3*HH;       // whh MFMA frags (GRU2)

  // one-time weight prep
  wfrag_k<<<(384*64 + 255)/256, 256, 0, stream>>>(r1_whh, WF1);
  wfrag_k<<<(384*64 + 255)/256, 256, 0, stream>>>(r2_whh, WF2);
  split_w_k<<<(HH*HH + 255)/256, 256, 0, stream>>>(conv2_w, C2H, C2L, HH*HH);
  split_w_k<<<(G3*HH + 255)/256, 256, 0, stream>>>(r1_wih, WI1H, WI1L, G3*HH);
  split_w_k<<<(G3*HH + 255)/256, 256, 0, stream>>>(r2_wih, WI2H, WI2L, G3*HH);
  split_w_k<<<(HH*2*HH + 255)/256, 256, 0, stream>>>(r1_cw, CW1H, CW1L, HH*2*HH);
  split_w_k<<<(HH*2*HH + 255)/256, 256, 0, stream>>>(r2_cw, CW2H, CW2L, HH*2*HH);

  const int MB = Ri/128;

  // ---------- pass A: comb -> XcF; conv1 BN1 stats FUSED (no store) ----------
  gemm_tn<0,1><<<dim3(SB/128,1), 256, 0, stream>>>(X, II, comb_w, 80, comb_b, XcF, CC, SB, CC, 80, Mi, 0, nullptr, nullptr, 0);
  gemm_tn<3,0><<<dim3(SB/128,2), 256, 0, stream>>>(XcF, CC, conv1_w, CC, conv1_b, nullptr, 0, SB, HH, CC, nullptr, 0, PS, PQ, 0);
  bn_final_k<<<256, 256, 0, stream>>>(PS, PQ, bn1_g, bn1_b, SCv, SHv, SB/128);
  fold_k<<<(256*40 + 255)/256, 256, 0, stream>>>(conv1_w, conv1_b, SCv, SHv, W1F, B1F, 40);

  // ---------- pass B: FULLY FUSED conv2 stats (out1r recomputed in-kernel) ----------
  conv2stats_k<<<dim3(SB/128, 2), 256, 0, stream>>>(XcF, W1F, B1F, C2H, C2L, conv2_b, PS, PQ);
  bn_final_k<<<256, 256, 0, stream>>>(PS, PQ, bn2_g, bn2_b, SCv, SHv, SB/128);
  fold_k<<<(256*256 + 255)/256, 256, 0, stream>>>(conv2_w, conv2_b, SCv, SHv, W2F, B2F, 256);
  split_w_k<<<(HH*HH + 255)/256, 256, 0, stream>>>(W2F, W2FH, W2FL, HH*HH);

  // ---------- h0 -> carries ----------
  h0_k<<<BB, HH, 0, stream>>>(X, i2h_w, i2h_b, H1C, H2C);

  // ---------- pass C: pipelined main loop ----------
  for (int c=0;c<nchunks;c++){
    long long r0 = (long long)c*R;
    long long rp = r0 - (long long)R;
    // ---- S1(c): {res, out1r} fused, then hx, gi1
    gemm_tn_dual2<<<dim3(MB,2), 256, 0, stream>>>(X, r0, down_w, down_b, A,
                                                  XcF + r0*CC, W1F, B1F, Ee, Ri);
    gemm_mfp<2><<<dim3(MB,2), 256, 0, stream>>>(Ee, HH, W2FH, W2FL, HH, B2F, A, HH, HH, HH);     // hx
    gemm_mfp<0><<<dim3(MB,6), 256, 0, stream>>>(A, HH, WI1H, WI1L, HH, r1_bih, GI1, G3, G3, HH); // gi1
    // ---- fused scan: GRU1(c) || GRU2(c-1)
    gru_scan_mfma_k<<<2*(BB/4), 512, 0, stream>>>(
        GI1, WF1, r1_bhh, mask + r0, H1C, Ee, sc_chunk,
        GI2, WF2, r2_bhh, (c > 0) ? (mask + rp) : mask, H2C, Hh2, (c > 0) ? sc_chunk : 0);
    // ---- S3(c-1): finish previous chunk
    if (c > 0){
      gemm_mfp_dual<<<dim3(MB,2), 256, 0, stream>>>(Hx1, Hh2, CW2H, CW2L, r2_cb, Cxp, HH, HH);   // outs2
      head_ln_k<<<Ri, 256, 0, stream>>>(Cxp, ln2_g, ln2_b, nn1_w, nn1_b, ln3_g, ln3_b, nn2_w, nn2_b, outp, rp);
    }
    // ---- S2(c): GRU1 out-projection, LN1, gi2(c)
    gemm_mfp_dual<<<dim3(MB,2), 256, 0, stream>>>(A, Ee, CW1H, CW1L, r1_cb, Cxp, HH, HH);        // outs1
    ln_rows_k<<<Ri, 256, 0, stream>>>(Cxp, Hx1, ln1_g, ln1_b);                                    // hx1(c)
    gemm_mfp<0><<<dim3(MB,6), 256, 0, stream>>>(Hx1, HH, WI2H, WI2L, HH, r2_bih, GI2, G3, G3, HH); // gi2(c)
  }
  // ---------- drain: GRU2(last chunk) ----------
  {
    long long rl = (long long)(nchunks-1)*R;
    gru_scan_mfma_k<<<2*(BB/4), 512, 0, stream>>>(
        GI1, WF1, r1_bhh, mask, H1C, Ee, 0,
        GI2, WF2, r2_bhh, mask + rl, H2C, Hh2, sc_chunk);
    gemm_mfp_dual<<<dim3(MB,2), 256, 0, stream>>>(Hx1, Hh2, CW2H, CW2L, r2_cb, Cxp, HH, HH);
    head_ln_k<<<Ri, 256, 0, stream>>>(Cxp, ln2_g, ln2_b, nn1_w, nn1_b, ln3_g, ln3_b, nn2_w, nn2_b, outp, rl);
  }
}

// Round 14
// 5417.952 us; speedup vs baseline: 1.3955x; 1.3955x over previous
//
#include <hip/hip_runtime.h>
#include <hip/hip_bf16.h>

// Problem dims
#define SS 256
#define BB 512
#define II 46
#define HH 256
#define CC 40
#define SB (SS*BB)        // 131072 rows
#define G3 (3*HH)         // 768
#define EPSF 1e-5f
#define NPART (SB/64)     // PS/PQ capacity (we use <=1024 rows)

typedef __attribute__((ext_vector_type(8))) short bf16x8;
typedef __attribute__((ext_vector_type(4))) float f32x4;

// ---------------------------------------------------------------------------
// helpers
// ---------------------------------------------------------------------------
__device__ __forceinline__ unsigned short f2bf_rne(float f){
  unsigned u = __float_as_uint(f);
  unsigned r = (u + 0x7FFFu + ((u >> 16) & 1u)) >> 16;
  return (unsigned short)r;
}
__device__ __forceinline__ float bf2f(unsigned short b){
  return __uint_as_float(((unsigned)b) << 16);
}
__device__ __forceinline__ void cvt8(const float* v, bf16x8& hi, bf16x8& lo){
  #pragma unroll
  for (int e=0;e<8;e++){
    unsigned short hb = f2bf_rne(v[e]);
    hi[e] = (short)hb;
    lo[e] = (short)f2bf_rne(v[e] - bf2f(hb));
  }
}

// ---------------------------------------------------------------------------
// split f32 weight array -> bf16 {hi, lo}
// ---------------------------------------------------------------------------
__global__ void split_w_k(const float* __restrict__ w, unsigned short* __restrict__ wh,
                          unsigned short* __restrict__ wl, int n){
  int i = blockIdx.x*256 + threadIdx.x;
  if (i >= n) return;
  float v = w[i];
  unsigned short hb = f2bf_rne(v);
  wh[i] = hb;
  wl[i] = f2bf_rne(v - bf2f(hb));
}

// ---------------------------------------------------------------------------
// h0[b,j] = sum_{c<6} X[0,b,40+c] * i2h_w[j,c] + i2h_b[j]  -> both carries
// ---------------------------------------------------------------------------
__global__ void h0_k(const float* __restrict__ X, const float* __restrict__ w,
                     const float* __restrict__ bias, float* __restrict__ h1c,
                     float* __restrict__ h2c){
  int b = blockIdx.x, jj = threadIdx.x;
  const float* p = X + (long long)b*II + (II - 6);
  float acc = bias[jj];
  #pragma unroll
  for (int c2=0;c2<6;c2++) acc = fmaf(p[c2], w[jj*6 + c2], acc);
  h1c[(long long)b*HH + jj] = acc;
  h2c[(long long)b*HH + jj] = acc;
}

// ---------------------------------------------------------------------------
// Pre-format whh (768x256) into MFMA B-fragment order, bf16 (R10, proven).
// ---------------------------------------------------------------------------
__global__ void wfrag_k(const float* __restrict__ whh, unsigned short* __restrict__ wf){
  int tid = blockIdx.x*256 + threadIdx.x;       // 384*64 = 24576 total
  if (tid >= 384*64) return;
  int f = tid >> 6, l = tid & 63;
  int ntile = f >> 3, kt = f & 7;
  int col = ntile*16 + (l & 15);
  int k0  = kt*32 + (l >> 4)*8;
  unsigned short* dst = wf + (((size_t)f)*64 + l)*8;
  #pragma unroll
  for (int e=0;e<8;e++) dst[e] = f2bf_rne(whh[(size_t)col*HH + k0 + e]);
}

// ---------------------------------------------------------------------------
// Generic f32 GEMM (small-K ops: comb K=80, conv1 K=40).
// MODE 0: store; 1: store relu; 2: accumulate; 3: BN-STATS ONLY (no store:
//   per-column sum/sumsq of (acc+bias) -> ps/pq[(pblk0+bx)*HH + col]).
// XM 1: A is implicit [X | Mi] with row stride II; A=X base, A2=Mi base, +r0.
// ---------------------------------------------------------------------------
template<int MODE, int XM>
__global__ void gemm_tn(const float* __restrict__ A, int lda,
                        const float* __restrict__ W, int ldw,
                        const float* __restrict__ bias,
                        float* __restrict__ Co, int ldc,
                        int Mrows, int N, int K,
                        const float* __restrict__ A2, long long r0,
                        float* __restrict__ ps, float* __restrict__ pq, int pblk0)
{
  __shared__ __align__(16) float As[32][132];
  __shared__ __align__(16) float Ws[32][132];
  const int m0 = blockIdx.x*128, n0 = blockIdx.y*128;
  const int t  = threadIdx.x;
  const int tm = t >> 4, tn = t & 15;
  float acc[8][8];
  #pragma unroll
  for (int i=0;i<8;i++)
    #pragma unroll
    for (int j2=0;j2<8;j2++) acc[i][j2] = 0.f;

  for (int k0=0;k0<K;k0+=32){
    #pragma unroll
    for (int u=0;u<16;u++){
      int idx = u*256 + t;
      int r = idx >> 5, c = idx & 31;
      int gk = k0 + c;
      float av = 0.f, wv = 0.f;
      if (gk < K){
        int gm = m0 + r;
        if (gm < Mrows){
          if (XM){
            long long gr = r0 + gm;
            av = (gk < CC) ? A[gr*II + gk] : A2[gr*II + (gk - CC)];
          } else {
            av = A[(long long)gm*lda + gk];
          }
        }
        int gn = n0 + r;
        if (gn < N)     wv = W[(long long)gn*ldw + gk];
      }
      As[c][r] = av;
      Ws[c][r] = wv;
    }
    __syncthreads();
    #pragma unroll
    for (int kk=0;kk<32;kk++){
      const float4 a0 = *(const float4*)&As[kk][tm*8];
      const float4 a1 = *(const float4*)&As[kk][tm*8+4];
      const float4 b0 = *(const float4*)&Ws[kk][tn*8];
      const float4 b1 = *(const float4*)&Ws[kk][tn*8+4];
      const float av[8] = {a0.x,a0.y,a0.z,a0.w,a1.x,a1.y,a1.z,a1.w};
      const float bv[8] = {b0.x,b0.y,b0.z,b0.w,b1.x,b1.y,b1.z,b1.w};
      #pragma unroll
      for (int i=0;i<8;i++)
        #pragma unroll
        for (int j2=0;j2<8;j2++) acc[i][j2] = fmaf(av[i], bv[j2], acc[i][j2]);
    }
    __syncthreads();
  }

  if (MODE == 3){
    __shared__ float redS[16][128];
    __shared__ float redQ[16][128];
    #pragma unroll
    for (int j2=0;j2<8;j2++){
      const int gn = n0 + tn*8 + j2;
      const float bv = bias[gn];
      float s = 0.f, q = 0.f;
      #pragma unroll
      for (int i=0;i<8;i++){
        const float val = acc[i][j2] + bv;
        s += val; q = fmaf(val, val, q);
      }
      redS[tm][tn*8+j2] = s;
      redQ[tm][tn*8+j2] = q;
    }
    __syncthreads();
    if (t < 128){
      float ss = 0.f, qq = 0.f;
      #pragma unroll
      for (int m=0;m<16;m++){ ss += redS[m][t]; qq += redQ[m][t]; }
      ps[(size_t)(pblk0 + blockIdx.x)*HH + n0 + t] = ss;
      pq[(size_t)(pblk0 + blockIdx.x)*HH + n0 + t] = qq;
    }
    return;
  }

  const bool fullc = (n0 + 128 <= N);
  #pragma unroll
  for (int i=0;i<8;i++){
    int gm = m0 + tm*8 + i;
    if (gm < Mrows){
      if (fullc){
        float v[8];
        #pragma unroll
        for (int j2=0;j2<8;j2++){
          int gn = n0 + tn*8 + j2;
          float val = acc[i][j2] + bias[gn];
          if (MODE == 1) val = fmaxf(val, 0.f);
          v[j2] = val;
        }
        float* cp = &Co[(long long)gm*ldc + n0 + tn*8];
        if (MODE == 2){
          float4 o0 = *(float4*)cp, o1 = *(float4*)(cp+4);
          v[0]+=o0.x; v[1]+=o0.y; v[2]+=o0.z; v[3]+=o0.w;
          v[4]+=o1.x; v[5]+=o1.y; v[6]+=o1.z; v[7]+=o1.w;
        }
        *(float4*)cp     = make_float4(v[0],v[1],v[2],v[3]);
        *(float4*)(cp+4) = make_float4(v[4],v[5],v[6],v[7]);
      } else {
        #pragma unroll
        for (int j2=0;j2<8;j2++){
          int gn = n0 + tn*8 + j2;
          if (gn < N){
            long long oi = (long long)gm*ldc + gn;
            float val = acc[i][j2] + bias[gn];
            if (MODE == 1) val = fmaxf(val, 0.f);
            if (MODE == 2) val += Co[oi];
            Co[oi] = val;
          }
        }
      }
    }
  }
}

// ---------------------------------------------------------------------------
// Dual-output small-K GEMM (S1 fusion): res + relu(out1) in one dispatch.
// ---------------------------------------------------------------------------
__global__ void gemm_tn_dual2(const float* __restrict__ Xb, long long r0,
                              const float* __restrict__ W1, const float* __restrict__ b1,
                              float* __restrict__ Co1,
                              const float* __restrict__ A2, const float* __restrict__ W2,
                              const float* __restrict__ b2, float* __restrict__ Co2,
                              int Mrows)
{
  __shared__ __align__(16) float As1[32][132];
  __shared__ __align__(16) float As2[32][132];
  __shared__ __align__(16) float Ws1[32][132];
  __shared__ __align__(16) float Ws2[32][132];
  const int m0 = blockIdx.x*128, n0 = blockIdx.y*128;
  const int t  = threadIdx.x;
  const int tm = t >> 4, tn = t & 15;
  float acc1[8][8], acc2[8][8];
  #pragma unroll
  for (int i=0;i<8;i++)
    #pragma unroll
    for (int j2=0;j2<8;j2++){ acc1[i][j2] = 0.f; acc2[i][j2] = 0.f; }

  for (int k0=0;k0<CC;k0+=32){
    #pragma unroll
    for (int u=0;u<16;u++){
      int idx = u*256 + t;
      int r = idx >> 5, c = idx & 31;
      int gk = k0 + c;
      float a1=0.f, a2=0.f, w1=0.f, w2=0.f;
      if (gk < CC){
        int gm = m0 + r;
        if (gm < Mrows){
          long long gr = r0 + gm;
          a1 = Xb[gr*II + gk];
          a2 = A2[(long long)gm*CC + gk];
        }
        int gn = n0 + r;
        w1 = W1[(long long)gn*CC + gk];
        w2 = W2[(long long)gn*CC + gk];
      }
      As1[c][r] = a1; As2[c][r] = a2;
      Ws1[c][r] = w1; Ws2[c][r] = w2;
    }
    __syncthreads();
    #pragma unroll
    for (int kk=0;kk<32;kk++){
      const float4 p0 = *(const float4*)&As1[kk][tm*8];
      const float4 p1 = *(const float4*)&As1[kk][tm*8+4];
      const float4 q0 = *(const float4*)&As2[kk][tm*8];
      const float4 q1 = *(const float4*)&As2[kk][tm*8+4];
      const float4 u0 = *(const float4*)&Ws1[kk][tn*8];
      const float4 u1 = *(const float4*)&Ws1[kk][tn*8+4];
      const float4 v0 = *(const float4*)&Ws2[kk][tn*8];
      const float4 v1 = *(const float4*)&Ws2[kk][tn*8+4];
      const float a1v[8] = {p0.x,p0.y,p0.z,p0.w,p1.x,p1.y,p1.z,p1.w};
      const float a2v[8] = {q0.x,q0.y,q0.z,q0.w,q1.x,q1.y,q1.z,q1.w};
      const float w1v[8] = {u0.x,u0.y,u0.z,u0.w,u1.x,u1.y,u1.z,u1.w};
      const float w2v[8] = {v0.x,v0.y,v0.z,v0.w,v1.x,v1.y,v1.z,v1.w};
      #pragma unroll
      for (int i=0;i<8;i++)
        #pragma unroll
        for (int j2=0;j2<8;j2++){
          acc1[i][j2] = fmaf(a1v[i], w1v[j2], acc1[i][j2]);
          acc2[i][j2] = fmaf(a2v[i], w2v[j2], acc2[i][j2]);
        }
    }
    __syncthreads();
  }
  #pragma unroll
  for (int i=0;i<8;i++){
    int gm = m0 + tm*8 + i;
    if (gm < Mrows){
      float v1[8], v2[8];
      #pragma unroll
      for (int j2=0;j2<8;j2++){
        int gn = n0 + tn*8 + j2;
        v1[j2] = acc1[i][j2] + b1[gn];
        v2[j2] = fmaxf(acc2[i][j2] + b2[gn], 0.f);
      }
      float* c1 = &Co1[(long long)gm*HH + n0 + tn*8];
      float* c2 = &Co2[(long long)gm*HH + n0 + tn*8];
      *(float4*)c1     = make_float4(v1[0],v1[1],v1[2],v1[3]);
      *(float4*)(c1+4) = make_float4(v1[4],v1[5],v1[6],v1[7]);
      *(float4*)c2     = make_float4(v2[0],v2[1],v2[2],v2[3]);
      *(float4*)(c2+4) = make_float4(v2[4],v2[5],v2[6],v2[7]);
    }
  }
}

// ---------------------------------------------------------------------------
// Split-bf16 MFMA GEMM with PRE-SPLIT B.
// MODE 0: store; 2: accumulate; 3: BN-STATS ONLY (no store).
// ---------------------------------------------------------------------------
template<int MODE>
__global__ __launch_bounds__(256) void gemm_mfp(
    const float* __restrict__ A, int lda,
    const unsigned short* __restrict__ Wh, const unsigned short* __restrict__ Wl, int ldw,
    const float* __restrict__ bias,
    float* __restrict__ Co, int ldc,
    int N, int K,
    float* __restrict__ ps, float* __restrict__ pq, int pblk0)
{
  __shared__ __align__(16) unsigned short Ah[128*32];
  __shared__ __align__(16) unsigned short Al[128*32];
  __shared__ __align__(16) unsigned short Bh[128*32];
  __shared__ __align__(16) unsigned short Bl[128*32];
  const int t = threadIdx.x;
  const int m0 = blockIdx.x*128, n0 = blockIdx.y*128;
  const int lane = t & 63, w = t >> 6;
  const int wm = (w & 1)*64, wn = (w >> 1)*64;
  const int fr = lane & 15, fg = lane >> 4;

  f32x4 acc[4][4];
  #pragma unroll
  for (int i=0;i<4;i++)
    #pragma unroll
    for (int j=0;j<4;j++){ f32x4 z; z[0]=0;z[1]=0;z[2]=0;z[3]=0; acc[i][j]=z; }

  for (int k0=0; k0<K; k0+=32){
    #pragma unroll
    for (int cc=0; cc<2; cc++){
      const int c   = t + cc*256;
      const int row = c >> 2, kg = c & 3;
      const int byte = row*64 + ((kg*16) ^ (((row>>1)&3)<<4));
      {
        const float* ap = A + (size_t)(m0+row)*lda + k0 + kg*8;
        float v[8];
        *(float4*)&v[0] = *(const float4*)ap;
        *(float4*)&v[4] = *(const float4*)(ap+4);
        bf16x8 hi, lo; cvt8(v, hi, lo);
        *(bf16x8*)((char*)Ah + byte) = hi;
        *(bf16x8*)((char*)Al + byte) = lo;
      }
      {
        const size_t off = (size_t)(n0+row)*ldw + k0 + kg*8;
        *(bf16x8*)((char*)Bh + byte) = *(const bf16x8*)&Wh[off];
        *(bf16x8*)((char*)Bl + byte) = *(const bf16x8*)&Wl[off];
      }
    }
    __syncthreads();
    bf16x8 ahi[4], alo[4], bhi[4], blo[4];
    #pragma unroll
    for (int mt=0; mt<4; mt++){
      const int r = wm + mt*16 + fr;
      const int byte = r*64 + ((fg*16) ^ (((r>>1)&3)<<4));
      ahi[mt] = *(const bf16x8*)((const char*)Ah + byte);
      alo[mt] = *(const bf16x8*)((const char*)Al + byte);
    }
    #pragma unroll
    for (int nt=0; nt<4; nt++){
      const int r = wn + nt*16 + fr;
      const int byte = r*64 + ((fg*16) ^ (((r>>1)&3)<<4));
      bhi[nt] = *(const bf16x8*)((const char*)Bh + byte);
      blo[nt] = *(const bf16x8*)((const char*)Bl + byte);
    }
    #pragma unroll
    for (int mt=0; mt<4; mt++)
      #pragma unroll
      for (int nt=0; nt<4; nt++){
        acc[mt][nt] = __builtin_amdgcn_mfma_f32_16x16x32_bf16(alo[mt], bhi[nt], acc[mt][nt], 0,0,0);
        acc[mt][nt] = __builtin_amdgcn_mfma_f32_16x16x32_bf16(ahi[mt], blo[nt], acc[mt][nt], 0,0,0);
        acc[mt][nt] = __builtin_amdgcn_mfma_f32_16x16x32_bf16(ahi[mt], bhi[nt], acc[mt][nt], 0,0,0);
      }
    __syncthreads();
  }

  if (MODE == 3){
    __shared__ float swS[4][4][16];
    __shared__ float qwS[4][4][16];
    float sv[4], qv[4];
    #pragma unroll
    for (int nt=0; nt<4; nt++){
      const int col = n0 + wn + nt*16 + fr;
      const float bv = bias[col];
      float s = 0.f, q = 0.f;
      #pragma unroll
      for (int mt=0; mt<4; mt++)
        #pragma unroll
        for (int i=0;i<4;i++){
          const float val = acc[mt][nt][i] + bv;
          s += val; q = fmaf(val, val, q);
        }
      s += __shfl_down(s, 32); q += __shfl_down(q, 32);
      s += __shfl_down(s, 16); q += __shfl_down(q, 16);
      sv[nt] = s; qv[nt] = q;
    }
    if (fg == 0){
      #pragma unroll
      for (int nt=0; nt<4; nt++){ swS[w][nt][fr] = sv[nt]; qwS[w][nt][fr] = qv[nt]; }
    }
    __syncthreads();
    if ((w & 1) == 0 && lane < 16){
      #pragma unroll
      for (int nt=0; nt<4; nt++){
        const int col = n0 + wn + nt*16 + fr;
        ps[(size_t)(pblk0 + blockIdx.x)*HH + col] = swS[w][nt][fr] + swS[w+1][nt][fr];
        pq[(size_t)(pblk0 + blockIdx.x)*HH + col] = qwS[w][nt][fr] + qwS[w+1][nt][fr];
      }
    }
    return;
  }

  #pragma unroll
  for (int mt=0; mt<4; mt++){
    #pragma unroll
    for (int nt=0; nt<4; nt++){
      const int col = n0 + wn + nt*16 + fr;
      const float bv = bias[col];
      #pragma unroll
      for (int i=0;i<4;i++){
        const int row = m0 + wm + mt*16 + fg*4 + i;
        const size_t oi = (size_t)row*ldc + col;
        float val = acc[mt][nt][i] + bv;
        if (MODE == 2) val += Co[oi];
        Co[oi] = val;
      }
    }
  }
}

// ---------------------------------------------------------------------------
// Dual-A fused out-projection GEMM with pre-split B (cw).
// ---------------------------------------------------------------------------
__global__ __launch_bounds__(256) void gemm_mfp_dual(
    const float* __restrict__ A1, const float* __restrict__ A2,
    const unsigned short* __restrict__ Wh, const unsigned short* __restrict__ Wl,
    const float* __restrict__ bias,
    float* __restrict__ Co, int ldc, int N)
{
  __shared__ __align__(16) unsigned short Ah[128*32];
  __shared__ __align__(16) unsigned short Al[128*32];
  __shared__ __align__(16) unsigned short Bh[128*32];
  __shared__ __align__(16) unsigned short Bl[128*32];
  const int t = threadIdx.x;
  const int m0 = blockIdx.x*128, n0 = blockIdx.y*128;
  const int lane = t & 63, w = t >> 6;
  const int wm = (w & 1)*64, wn = (w >> 1)*64;
  const int fr = lane & 15, fg = lane >> 4;

  f32x4 acc[4][4];
  #pragma unroll
  for (int i=0;i<4;i++)
    #pragma unroll
    for (int j=0;j<4;j++){ f32x4 z; z[0]=0;z[1]=0;z[2]=0;z[3]=0; acc[i][j]=z; }

  for (int k0=0; k0<2*HH; k0+=32){
    const float* Abase = (k0 < HH) ? A1 : A2;
    const int    kofs  = (k0 < HH) ? k0 : (k0 - HH);
    #pragma unroll
    for (int cc=0; cc<2; cc++){
      const int c   = t + cc*256;
      const int row = c >> 2, kg = c & 3;
      const int byte = row*64 + ((kg*16) ^ (((row>>1)&3)<<4));
      {
        const float* ap = Abase + (size_t)(m0+row)*HH + kofs + kg*8;
        float v[8];
        *(float4*)&v[0] = *(const float4*)ap;
        *(float4*)&v[4] = *(const float4*)(ap+4);
        bf16x8 hi, lo; cvt8(v, hi, lo);
        *(bf16x8*)((char*)Ah + byte) = hi;
        *(bf16x8*)((char*)Al + byte) = lo;
      }
      {
        const size_t off = (size_t)(n0+row)*(2*HH) + k0 + kg*8;
        *(bf16x8*)((char*)Bh + byte) = *(const bf16x8*)&Wh[off];
        *(bf16x8*)((char*)Bl + byte) = *(const bf16x8*)&Wl[off];
      }
    }
    __syncthreads();
    bf16x8 ahi[4], alo[4], bhi[4], blo[4];
    #pragma unroll
    for (int mt=0; mt<4; mt++){
      const int r = wm + mt*16 + fr;
      const int byte = r*64 + ((fg*16) ^ (((r>>1)&3)<<4));
      ahi[mt] = *(const bf16x8*)((const char*)Ah + byte);
      alo[mt] = *(const bf16x8*)((const char*)Al + byte);
    }
    #pragma unroll
    for (int nt=0; nt<4; nt++){
      const int r = wn + nt*16 + fr;
      const int byte = r*64 + ((fg*16) ^ (((r>>1)&3)<<4));
      bhi[nt] = *(const bf16x8*)((const char*)Bh + byte);
      blo[nt] = *(const bf16x8*)((const char*)Bl + byte);
    }
    #pragma unroll
    for (int mt=0; mt<4; mt++)
      #pragma unroll
      for (int nt=0; nt<4; nt++){
        acc[mt][nt] = __builtin_amdgcn_mfma_f32_16x16x32_bf16(alo[mt], bhi[nt], acc[mt][nt], 0,0,0);
        acc[mt][nt] = __builtin_amdgcn_mfma_f32_16x16x32_bf16(ahi[mt], blo[nt], acc[mt][nt], 0,0,0);
        acc[mt][nt] = __builtin_amdgcn_mfma_f32_16x16x32_bf16(ahi[mt], bhi[nt], acc[mt][nt], 0,0,0);
      }
    __syncthreads();
  }

  #pragma unroll
  for (int mt=0; mt<4; mt++){
    #pragma unroll
    for (int nt=0; nt<4; nt++){
      const int col = n0 + wn + nt*16 + fr;
      const float bv = bias[col];
      #pragma unroll
      for (int i=0;i<4;i++){
        const int row = m0 + wm + mt*16 + fg*4 + i;
        const size_t oi = (size_t)row*ldc + col;
        Co[oi] = acc[mt][nt][i] + bv;
      }
    }
  }
}

// ---------------------------------------------------------------------------
// BN final — PARALLEL (R12, proven): 256 blocks (one per channel).
// ---------------------------------------------------------------------------
__global__ void bn_final_k(const float* __restrict__ ps, const float* __restrict__ pq,
                           const float* __restrict__ g, const float* __restrict__ b,
                           float* __restrict__ sc, float* __restrict__ sh, int npart){
  const int col = blockIdx.x;
  const int t = threadIdx.x;
  double s = 0.0, q = 0.0;
  for (int i=t; i<npart; i+=256){
    s += (double)ps[(size_t)i*HH + col];
    q += (double)pq[(size_t)i*HH + col];
  }
  __shared__ double sd[256], qd[256];
  sd[t] = s; qd[t] = q;
  __syncthreads();
  for (int o=128;o>0;o>>=1){
    if (t < o){ sd[t] += sd[t+o]; qd[t] += qd[t+o]; }
    __syncthreads();
  }
  if (t == 0){
    double mu  = sd[0] / (double)SB;
    double var = qd[0] / (double)SB - mu*mu;
    float scv = (float)((double)g[col] / sqrt(var + 1e-5));
    sc[col] = scv;
    sh[col] = (float)((double)b[col] - mu*(double)scv);
  }
}

__global__ void fold_k(const float* __restrict__ w, const float* __restrict__ b,
                       const float* __restrict__ sc, const float* __restrict__ sh,
                       float* __restrict__ wf, float* __restrict__ bf, int K){
  int idx = blockIdx.x*blockDim.x + threadIdx.x;
  if (idx < 256*K){ int o = idx / K; wf[idx] = w[idx]*sc[o]; }
  if (idx < 256)  bf[idx] = b[idx]*sc[idx] + sh[idx];
}

// ---------------------------------------------------------------------------
// LayerNorm over last dim (256), out-of-place. One block per row.
// ---------------------------------------------------------------------------
__global__ void ln_rows_k(const float* __restrict__ Xi, float* __restrict__ Xo,
                          const float* __restrict__ g, const float* __restrict__ b){
  long long row = blockIdx.x;
  int t = threadIdx.x;
  float v = Xi[row*HH + t];
  float s = v, q = v*v;
  #pragma unroll
  for (int o=32;o>0;o>>=1){ s += __shfl_down(s,o); q += __shfl_down(q,o); }
  __shared__ float ssm[4], qqm[4];
  int w = t >> 6;
  if ((t & 63) == 0){ ssm[w] = s; qqm[w] = q; }
  __syncthreads();
  if (t == 0){ ssm[0] = ssm[0]+ssm[1]+ssm[2]+ssm[3]; qqm[0] = qqm[0]+qqm[1]+qqm[2]+qqm[3]; }
  __syncthreads();
  s = ssm[0]; q = qqm[0];
  float mu  = s * (1.f/HH);
  float var = q * (1.f/HH) - mu*mu;
  float rs  = rsqrtf(var + EPSF);
  Xo[row*HH + t] = (v - mu)*rs*g[t] + b[t];
}

// ---------------------------------------------------------------------------
// FUSED dual-GRU gate scan — MFMA edition (R10, proven).
// ---------------------------------------------------------------------------
__global__ __launch_bounds__(512) void gru_scan_mfma_k(
  const float* __restrict__ gi1, const unsigned short* __restrict__ wf1,
  const float* __restrict__ b1v, const float* __restrict__ m1v,
  float* __restrict__ hc1, float* __restrict__ Hh1o, int nst1,
  const float* __restrict__ gi2, const unsigned short* __restrict__ wf2,
  const float* __restrict__ b2v, const float* __restrict__ m2v,
  float* __restrict__ hc2, float* __restrict__ Hh2o, int nst2)
{
  const int gsel = blockIdx.x & 1;
  const int blk  = blockIdx.x >> 1;
  const float* gi    = gsel ? gi2 : gi1;
  const unsigned short* wfr = gsel ? wf2 : wf1;
  const float* bhh   = gsel ? b2v : b1v;
  const float* mask0 = gsel ? m2v : m1v;
  float* hcar        = gsel ? hc2 : hc1;
  float* Hh          = gsel ? Hh2o : Hh1o;
  const int nst      = gsel ? nst2 : nst1;
  if (nst <= 0) return;

  const int t    = threadIdx.x;
  const int b0   = blk*4;
  const int lane = t & 63, wid = t >> 6;      // 8 waves
  const int arow = lane & 15, kg = lane >> 4; // A-fragment coords
  const bool act = (arow < 4);
  const int uj = t & 255, ur = t >> 8;        // gate coords: rows ur, ur+2

  __shared__ __align__(16) unsigned short AhS[4][256];
  __shared__ __align__(16) unsigned short AlS[4][256];
  __shared__ __align__(16) float ghS[4][768];
  __shared__ float mkz[4];

  float hold0 = hcar[(size_t)(b0+ur  )*HH + uj];
  float hold1 = hcar[(size_t)(b0+ur+2)*HH + uj];
  const float br = bhh[uj], bz = bhh[uj+HH], bn_ = bhh[uj+2*HH];

  {
    unsigned short hb0 = f2bf_rne(hold0);
    AhS[ur  ][uj] = hb0;  AlS[ur  ][uj] = f2bf_rne(hold0 - bf2f(hb0));
    unsigned short hb1 = f2bf_rne(hold1);
    AhS[ur+2][uj] = hb1;  AlS[ur+2][uj] = f2bf_rne(hold1 - bf2f(hb1));
  }
  __syncthreads();

  const unsigned short* wfbase = wfr + (((size_t)(wid*6)*8)*64 + lane)*8;

  for (int st=0; st<nst; ++st){
    const size_t ga = ((size_t)st*BB + b0 + ur  )*G3 + uj;
    const size_t gb = ((size_t)st*BB + b0 + ur+2)*G3 + uj;
    const float i0r=gi[ga], i0z=gi[ga+HH], i0n=gi[ga+2*HH];
    const float i1r=gi[gb], i1z=gi[gb+HH], i1n=gi[gb+2*HH];
    if (t < 4) mkz[t] = mask0[(size_t)st*BB + b0 + t];

    bf16x8 AH[8], AL[8];
    #pragma unroll
    for (int kt=0; kt<8; kt++){
      if (act){
        AH[kt] = *(const bf16x8*)&AhS[arow][kt*32 + kg*8];
        AL[kt] = *(const bf16x8*)&AlS[arow][kt*32 + kg*8];
      } else {
        bf16x8 z = {0,0,0,0,0,0,0,0};
        AH[kt] = z; AL[kt] = z;
      }
    }
    #pragma unroll
    for (int nt=0; nt<6; nt++){
      const unsigned short* wp = wfbase + (size_t)nt*8*64*8;
      f32x4 acc = {0.f,0.f,0.f,0.f};
      #pragma unroll
      for (int kt=0; kt<8; kt++){
        const bf16x8 b = *(const bf16x8*)(wp + (size_t)kt*64*8);
        acc = __builtin_amdgcn_mfma_f32_16x16x32_bf16(AL[kt], b, acc, 0,0,0);
        acc = __builtin_amdgcn_mfma_f32_16x16x32_bf16(AH[kt], b, acc, 0,0,0);
      }
      if (lane < 16){
        const int col = (wid*6 + nt)*16 + lane;
        ghS[0][col] = acc[0];
        ghS[1][col] = acc[1];
        ghS[2][col] = acc[2];
        ghS[3][col] = acc[3];
      }
    }
    __syncthreads();

    {
      const float ar = ghS[ur][uj]       + br;
      const float az = ghS[ur][uj+HH]    + bz;
      const float an = ghS[ur][uj+2*HH]  + bn_;
      const float rr = 1.f/(1.f + __expf(-(i0r + ar)));
      const float zz = 1.f/(1.f + __expf(-(i0z + az)));
      const float nn = tanhf(fmaf(rr, an, i0n));
      const float m  = mkz[ur];
      const float hnew = (1.f - zz)*nn + zz*hold0;
      const float hv = hnew*m + hold0*(1.f - m);
      hold0 = hv;
      unsigned short hb = f2bf_rne(hv);
      AhS[ur][uj] = hb; AlS[ur][uj] = f2bf_rne(hv - bf2f(hb));
      Hh[((size_t)st*BB + b0 + ur)*HH + uj] = hv;
    }
    {
      const int r_ = ur + 2;
      const float ar = ghS[r_][uj]       + br;
      const float az = ghS[r_][uj+HH]    + bz;
      const float an = ghS[r_][uj+2*HH]  + bn_;
      const float rr = 1.f/(1.f + __expf(-(i1r + ar)));
      const float zz = 1.f/(1.f + __expf(-(i1z + az)));
      const float nn = tanhf(fmaf(rr, an, i1n));
      const float m  = mkz[r_];
      const float hnew = (1.f - zz)*nn + zz*hold1;
      const float hv = hnew*m + hold1*(1.f - m);
      hold1 = hv;
      unsigned short hb = f2bf_rne(hv);
      AhS[r_][uj] = hb; AlS[r_][uj] = f2bf_rne(hv - bf2f(hb));
      Hh[((size_t)st*BB + b0 + r_)*HH + uj] = hv;
    }
    __syncthreads();
  }
  hcar[(size_t)(b0+ur  )*HH + uj] = hold0;
  hcar[(size_t)(b0+ur+2)*HH + uj] = hold1;
}

// ---------------------------------------------------------------------------
// Head (fused LN2): x=LN2(row); relu(x@nn1.T+b1) -> LN(8) -> @nn2.T+b2.
// ---------------------------------------------------------------------------
__global__ void head_ln_k(const float* __restrict__ hx,
                          const float* __restrict__ g2, const float* __restrict__ b2,
                          const float* __restrict__ w1, const float* __restrict__ b1,
                          const float* __restrict__ g3, const float* __restrict__ b3,
                          const float* __restrict__ w2, const float* __restrict__ b2h,
                          float* __restrict__ outp, long long r0){
  long long row = blockIdx.x;
  int t = threadIdx.x;
  float v = hx[row*HH + t];
  float s = v, q = v*v;
  #pragma unroll
  for (int o=32;o>0;o>>=1){ s += __shfl_down(s,o); q += __shfl_down(q,o); }
  __shared__ float ssm[4], qqm[4];
  int w = t >> 6;
  if ((t & 63) == 0){ ssm[w] = s; qqm[w] = q; }
  __syncthreads();
  if (t == 0){ ssm[0] = ssm[0]+ssm[1]+ssm[2]+ssm[3]; qqm[0] = qqm[0]+qqm[1]+qqm[2]+qqm[3]; }
  __syncthreads();
  s = ssm[0]; q = qqm[0];
  float mu  = s * (1.f/HH);
  float var = q * (1.f/HH) - mu*mu;
  float rs  = rsqrtf(var + EPSF);
  __shared__ float xs[HH];
  xs[t] = (v - mu)*rs*g2[t] + b2[t];
  __syncthreads();
  int o = t >> 5, l = t & 31;
  const float* wv = w1 + o*HH;
  float acc = 0.f;
  for (int k=l;k<HH;k+=32) acc = fmaf(xs[k], wv[k], acc);
  #pragma unroll
  for (int d=16;d>0;d>>=1) acc += __shfl_down(acc, d, 32);
  __shared__ float a8[8];
  if (l == 0) a8[o] = fmaxf(acc + b1[o], 0.f);
  __syncthreads();
  if (t == 0){
    float ss = 0.f;
    #pragma unroll
    for (int i=0;i<8;i++) ss += a8[i];
    float m8 = ss*0.125f;
    float qq = 0.f;
    #pragma unroll
    for (int i=0;i<8;i++){ float d = a8[i]-m8; qq = fmaf(d,d,qq); }
    float r8 = rsqrtf(qq*0.125f + EPSF);
    float y0 = b2h[0], y1 = b2h[1];
    #pragma unroll
    for (int i=0;i<8;i++){
      float vv = (a8[i]-m8)*r8*g3[i] + b3[i];
      y0 = fmaf(vv, w2[i],   y0);
      y1 = fmaf(vv, w2[8+i], y1);
    }
    outp[(r0+row)*2+0] = y0; outp[(r0+row)*2+1] = y1;
  }
}

// ---------------------------------------------------------------------------
// Host launcher. R14 = exact revert to R12 (proven best, 5522us).
// R13's conv2stats fusion refuted: scalar W1F/LDS load chains at 12%
// occupancy -> 2368us/dispatch (latency-bound, VALUBusy 4.5%).
// ---------------------------------------------------------------------------
extern "C" void kernel_launch(void* const* d_in, const int* in_sizes, int n_in,
                              void* d_out, int out_size, void* d_ws, size_t ws_size,
                              hipStream_t stream) {
  const float* X      = (const float*)d_in[0];
  const float* Mi     = (const float*)d_in[1];
  const float* mask   = (const float*)d_in[2];
  const float* i2h_w  = (const float*)d_in[3];
  const float* i2h_b  = (const float*)d_in[4];
  const float* comb_w = (const float*)d_in[5];
  const float* comb_b = (const float*)d_in[6];
  const float* down_w = (const float*)d_in[7];
  const float* down_b = (const float*)d_in[8];
  const float* conv1_w= (const float*)d_in[9];
  const float* conv1_b= (const float*)d_in[10];
  const float* conv2_w= (const float*)d_in[11];
  const float* conv2_b= (const float*)d_in[12];
  const float* bn1_g  = (const float*)d_in[13];
  const float* bn1_b  = (const float*)d_in[14];
  const float* bn2_g  = (const float*)d_in[15];
  const float* bn2_b  = (const float*)d_in[16];
  const float* r1_wih = (const float*)d_in[17];
  const float* r1_whh = (const float*)d_in[18];
  const float* r1_bih = (const float*)d_in[19];
  const float* r1_bhh = (const float*)d_in[20];
  const float* r1_cw  = (const float*)d_in[21];
  const float* r1_cb  = (const float*)d_in[22];
  const float* r2_wih = (const float*)d_in[23];
  const float* r2_whh = (const float*)d_in[24];
  const float* r2_bih = (const float*)d_in[25];
  const float* r2_bhh = (const float*)d_in[26];
  const float* r2_cw  = (const float*)d_in[27];
  const float* r2_cb  = (const float*)d_in[28];
  const float* ln1_g  = (const float*)d_in[29];
  const float* ln1_b  = (const float*)d_in[30];
  const float* ln2_g  = (const float*)d_in[31];
  const float* ln2_b  = (const float*)d_in[32];
  const float* ln3_g  = (const float*)d_in[33];
  const float* ln3_b  = (const float*)d_in[34];
  const float* nn1_w  = (const float*)d_in[35];
  const float* nn1_b  = (const float*)d_in[36];
  const float* nn2_w  = (const float*)d_in[37];
  const float* nn2_b  = (const float*)d_in[38];
  float* outp = (float*)d_out;

  const size_t us_elems = 2*((size_t)HH*HH + (size_t)HH*HH + (size_t)G3*HH
                           + (size_t)G3*HH + (size_t)HH*2*HH + (size_t)HH*2*HH)
                        + 2*(size_t)G3*HH;   // WF1/WF2
  const size_t tail_floats = 2*(size_t)BB*HH + 2*(size_t)NPART*HH + 2*HH
                           + (size_t)256*40 + 256 + (size_t)HH*HH + 256
                           + (size_t)SB*CC
                           + (us_elems + 1)/2;
  int cands[6] = {256,128,64,32,16,8};
  int sc_chunk = 0;
  for (int ci=0; ci<6; ci++){
    size_t R = (size_t)512*cands[ci];
    size_t need = (R*2560 + tail_floats)*sizeof(float);
    if (need <= ws_size && R*2560 >= (size_t)SB*HH){ sc_chunk = cands[ci]; break; }
  }
  if (!sc_chunk) return;

  const size_t R = (size_t)512*sc_chunk;     // rows per chunk
  const int Ri = (int)R;
  const int nchunks = SB / Ri;

  float* wsf = (float*)d_ws;
  float* A   = wsf;                    // R*256  (res -> hx)
  float* GI1 = A + R*HH;               // R*768  gi for GRU1(c)
  float* Cxp = GI1;                    // ALIAS: GI1 dead after scan; Cxp lives after
  float* GI2 = GI1 + R*G3;             // R*768  gi for GRU2(c)
  float* Ee  = GI2 + R*G3;             // R*256  out1r -> Hh1
  float* Hh2 = Ee + R*HH;              // R*256  Hh of GRU2(c-1)
  float* Hx1 = Hh2 + R*HH;             // R*256  hx1(c) = LN1 out
  float* tl  = Hx1 + R*HH;
  float* H1C = tl;                     // BB*HH
  float* H2C = H1C + (size_t)BB*HH;
  float* PS  = H2C + (size_t)BB*HH;    // NPART*HH (capacity)
  float* PQ  = PS  + (size_t)NPART*HH;
  float* SCv = PQ  + (size_t)NPART*HH; // HH
  float* SHv = SCv + HH;
  float* W1F = SHv + HH;               // 256*40
  float* B1F = W1F + (size_t)256*40;   // 256
  float* W2F = B1F + HH;               // 256*256
  float* B2F = W2F + (size_t)HH*HH;    // 256
  float* XcF = B2F + HH;               // SB*40 persisted comb output
  unsigned short* usb = (unsigned short*)(XcF + (size_t)SB*CC);
  unsigned short* C2H  = usb;                       // conv2_w raw split (HH*HH)
  unsigned short* C2L  = C2H  + (size_t)HH*HH;
  unsigned short* W2FH = C2L  + (size_t)HH*HH;      // folded conv2 (HH*HH)
  unsigned short* W2FL = W2FH + (size_t)HH*HH;
  unsigned short* WI1H = W2FL + (size_t)HH*HH;      // r1_wih (G3*HH)
  unsigned short* WI1L = WI1H + (size_t)G3*HH;
  unsigned short* WI2H = WI1L + (size_t)G3*HH;      // r2_wih (G3*HH)
  unsigned short* WI2L = WI2H + (size_t)G3*HH;
  unsigned short* CW1H = WI2L + (size_t)G3*HH;      // r1_cw (HH*2HH)
  unsigned short* CW1L = CW1H + (size_t)HH*2*HH;
  unsigned short* CW2H = CW1L + (size_t)HH*2*HH;    // r2_cw (HH*2HH)
  unsigned short* CW2L = CW2H + (size_t)HH*2*HH;
  unsigned short* WF1  = CW2L + (size_t)HH*2*HH;    // whh MFMA frags (GRU1)
  unsigned short* WF2  = WF1 + (size_t)G3*HH;       // whh MFMA frags (GRU2)

  // one-time weight prep
  wfrag_k<<<(384*64 + 255)/256, 256, 0, stream>>>(r1_whh, WF1);
  wfrag_k<<<(384*64 + 255)/256, 256, 0, stream>>>(r2_whh, WF2);
  split_w_k<<<(HH*HH + 255)/256, 256, 0, stream>>>(conv2_w, C2H, C2L, HH*HH);
  split_w_k<<<(G3*HH + 255)/256, 256, 0, stream>>>(r1_wih, WI1H, WI1L, G3*HH);
  split_w_k<<<(G3*HH + 255)/256, 256, 0, stream>>>(r2_wih, WI2H, WI2L, G3*HH);
  split_w_k<<<(HH*2*HH + 255)/256, 256, 0, stream>>>(r1_cw, CW1H, CW1L, HH*2*HH);
  split_w_k<<<(HH*2*HH + 255)/256, 256, 0, stream>>>(r2_cw, CW2H, CW2L, HH*2*HH);

  const int MB = Ri/128;

  // ---------- pass A: comb -> XcF; conv1 BN1 stats FUSED (no store) ----------
  gemm_tn<0,1><<<dim3(SB/128,1), 256, 0, stream>>>(X, II, comb_w, 80, comb_b, XcF, CC, SB, CC, 80, Mi, 0, nullptr, nullptr, 0);
  gemm_tn<3,0><<<dim3(SB/128,2), 256, 0, stream>>>(XcF, CC, conv1_w, CC, conv1_b, nullptr, 0, SB, HH, CC, nullptr, 0, PS, PQ, 0);
  bn_final_k<<<256, 256, 0, stream>>>(PS, PQ, bn1_g, bn1_b, SCv, SHv, SB/128);
  fold_k<<<(256*40 + 255)/256, 256, 0, stream>>>(conv1_w, conv1_b, SCv, SHv, W1F, B1F, 40);

  // ---------- pass B: out1r halves -> conv2 BN2 stats FUSED (no store) ----------
  {
    float* SA2 = wsf;                         // SB/2*HH scratch (per-chunk region is dead)
    for (int hlf=0; hlf<2; hlf++){
      long long r0 = (long long)hlf*(SB/2);
      gemm_tn<1,0><<<dim3(SB/256,2), 256, 0, stream>>>(XcF + r0*CC, CC, W1F, CC, B1F, SA2, HH, SB/2, HH, CC, nullptr, 0, nullptr, nullptr, 0);
      gemm_mfp<3><<<dim3(SB/256,2), 256, 0, stream>>>(SA2, HH, C2H, C2L, HH, conv2_b, nullptr, 0, HH, HH, PS, PQ, hlf*(SB/256));
    }
  }
  bn_final_k<<<256, 256, 0, stream>>>(PS, PQ, bn2_g, bn2_b, SCv, SHv, 2*(SB/256));
  fold_k<<<(256*256 + 255)/256, 256, 0, stream>>>(conv2_w, conv2_b, SCv, SHv, W2F, B2F, 256);
  split_w_k<<<(HH*HH + 255)/256, 256, 0, stream>>>(W2F, W2FH, W2FL, HH*HH);

  // ---------- h0 -> carries ----------
  h0_k<<<BB, HH, 0, stream>>>(X, i2h_w, i2h_b, H1C, H2C);

  // ---------- pass C: pipelined main loop ----------
  for (int c=0;c<nchunks;c++){
    long long r0 = (long long)c*R;
    long long rp = r0 - (long long)R;
    // ---- S1(c): {res, out1r} fused, then hx, gi1
    gemm_tn_dual2<<<dim3(MB,2), 256, 0, stream>>>(X, r0, down_w, down_b, A,
                                                  XcF + r0*CC, W1F, B1F, Ee, Ri);
    gemm_mfp<2><<<dim3(MB,2), 256, 0, stream>>>(Ee, HH, W2FH, W2FL, HH, B2F, A, HH, HH, HH, nullptr, nullptr, 0);     // hx
    gemm_mfp<0><<<dim3(MB,6), 256, 0, stream>>>(A, HH, WI1H, WI1L, HH, r1_bih, GI1, G3, G3, HH, nullptr, nullptr, 0); // gi1
    // ---- fused scan: GRU1(c) || GRU2(c-1)
    gru_scan_mfma_k<<<2*(BB/4), 512, 0, stream>>>(
        GI1, WF1, r1_bhh, mask + r0, H1C, Ee, sc_chunk,
        GI2, WF2, r2_bhh, (c > 0) ? (mask + rp) : mask, H2C, Hh2, (c > 0) ? sc_chunk : 0);
    // ---- S3(c-1): finish previous chunk
    if (c > 0){
      gemm_mfp_dual<<<dim3(MB,2), 256, 0, stream>>>(Hx1, Hh2, CW2H, CW2L, r2_cb, Cxp, HH, HH);   // outs2
      head_ln_k<<<Ri, 256, 0, stream>>>(Cxp, ln2_g, ln2_b, nn1_w, nn1_b, ln3_g, ln3_b, nn2_w, nn2_b, outp, rp);
    }
    // ---- S2(c): GRU1 out-projection, LN1, gi2(c)
    gemm_mfp_dual<<<dim3(MB,2), 256, 0, stream>>>(A, Ee, CW1H, CW1L, r1_cb, Cxp, HH, HH);        // outs1
    ln_rows_k<<<Ri, 256, 0, stream>>>(Cxp, Hx1, ln1_g, ln1_b);                                    // hx1(c)
    gemm_mfp<0><<<dim3(MB,6), 256, 0, stream>>>(Hx1, HH, WI2H, WI2L, HH, r2_bih, GI2, G3, G3, HH, nullptr, nullptr, 0); // gi2(c)
  }
  // ---------- drain: GRU2(last chunk) ----------
  {
    long long rl = (long long)(nchunks-1)*R;
    gru_scan_mfma_k<<<2*(BB/4), 512, 0, stream>>>(
        GI1, WF1, r1_bhh, mask, H1C, Ee, 0,
        GI2, WF2, r2_bhh, mask + rl, H2C, Hh2, sc_chunk);
    gemm_mfp_dual<<<dim3(MB,2), 256, 0, stream>>>(Hx1, Hh2, CW2H, CW2L, r2_cb, Cxp, HH, HH);
    head_ln_k<<<Ri, 256, 0, stream>>>(Cxp, ln2_g, ln2_b, nn1_w, nn1_b, ln3_g, ln3_b, nn2_w, nn2_b, outp, rl);
  }
}